// Round 12
// baseline (271.530 us; speedup 1.0000x reference)
//
#include <hip/hip_runtime.h>
#include <stdint.h>

#define B_ 2
#define S_ 2048
#define DM_ 2048
#define H_ 32
#define KVH_ 8
#define HD_ 64
#define NQK_ 3072   // 2048 q + 512 k + 512 v

typedef unsigned short u16;
typedef unsigned int u32;
typedef __attribute__((ext_vector_type(8))) short bf16x8;
typedef __attribute__((ext_vector_type(4))) float f32x4;

static __device__ __forceinline__ u16 f2bf(float f) {
  unsigned int u = __float_as_uint(f);
  u = (u + 0x7fffu + ((u >> 16) & 1u)) >> 16;
  return (u16)u;
}

// global -> LDS direct (width 16). LDS dest = wave-uniform base + lane*16.
static __device__ __forceinline__ void gload16(const void* g, void* lds_wave_base) {
  __builtin_amdgcn_global_load_lds(
      (__attribute__((address_space(1))) unsigned int*)(uintptr_t)g,
      (__attribute__((address_space(3))) unsigned int*)(uintptr_t)lds_wave_base,
      16, 0, 0);
}

// ---------------- fused fp32 -> bf16 convert (x, Wq, Wk, Wv, Wo) -----------
__global__ void cvt_all(const float* __restrict__ x, const float* __restrict__ wq,
                        const float* __restrict__ wk, const float* __restrict__ wv,
                        const float* __restrict__ wo,
                        u16* __restrict__ xb, u16* __restrict__ wbq,
                        u16* __restrict__ wbo) {
  const int NX = 2097152, NQ = 1048576, NKV = 262144;  // float4 counts
  const int TOT = NX + NQ + 2 * NKV + NQ;              // 4718592
  const int stride = gridDim.x * 256;
  for (int i = blockIdx.x * 256 + threadIdx.x; i < TOT; i += stride) {
    const float4* s; ushort4* d; int off;
    if (i < NX)                { s = (const float4*)x;  d = (ushort4*)xb;  off = i; }
    else if (i < NX + NQ)      { s = (const float4*)wq; d = (ushort4*)wbq; off = i - NX; }
    else if (i < NX + NQ + NKV){ s = (const float4*)wk; d = (ushort4*)(wbq + (size_t)DM_ * DM_); off = i - NX - NQ; }
    else if (i < NX + NQ + 2 * NKV) { s = (const float4*)wv; d = (ushort4*)(wbq + (size_t)DM_ * DM_ + (size_t)512 * DM_); off = i - NX - NQ - NKV; }
    else                       { s = (const float4*)wo; d = (ushort4*)wbo; off = i - NX - NQ - 2 * NKV; }
    const float4 v = s[off];
    ushort4 o;
    o.x = f2bf(v.x); o.y = f2bf(v.y); o.z = f2bf(v.z); o.w = f2bf(v.w);
    d[off] = o;
  }
}

// ---------------- GEMM: C(MxN) = A(MxK) * B(NxK)^T, bf16 in ----------------
// 2-phase double-buffered 128x128 (measured best structure; LDS b128 8-way
// aliasing is pigeonhole-structural at 64B rows — no swizzle can improve).
#define BM 128
#define BN 128
#define BK 32

#define GEMM_MAIN                                                               \
  __shared__ u16 As[2][BM * BK];                                                \
  __shared__ u16 Bs[2][BN * BK];                                                \
  const int t = threadIdx.x;                                                    \
  const int lane = t & 63;                                                      \
  const int w = t >> 6;                                                         \
  const int q = lane & 15, g = lane >> 4;                                       \
  const int wr = (w >> 1) * 64, wc = (w & 1) * 64;                              \
  const int m0 = blockIdx.y * BM;                                               \
  const int n0 = blockIdx.x * BN;                                               \
  f32x4 acc[4][4] = {};                                                         \
  const char* Ab = (const char*)A;                                              \
  const char* Bb = (const char*)Bw;                                             \
  const size_t K2 = (size_t)K * 2;                                              \
  const int P0 = t * 16;                                                        \
  const int row0 = P0 >> 6, kb0 = P0 & 63;                                      \
  const int P1 = 4096 + t * 16;                                                 \
  const int row1 = P1 >> 6, kb1 = P1 & 63;                                      \
  const int Pb0 = (w << 10), Pb1 = 4096 + (w << 10);                            \
  auto STAGE = [&](int buf, int k0) {                                           \
    gload16(Ab + (size_t)(m0 + row0) * K2 + (size_t)k0 * 2 + kb0, (char*)As[buf] + Pb0); \
    gload16(Ab + (size_t)(m0 + row1) * K2 + (size_t)k0 * 2 + kb1, (char*)As[buf] + Pb1); \
    gload16(Bb + (size_t)(n0 + row0) * K2 + (size_t)k0 * 2 + kb0, (char*)Bs[buf] + Pb0); \
    gload16(Bb + (size_t)(n0 + row1) * K2 + (size_t)k0 * 2 + kb1, (char*)Bs[buf] + Pb1); \
  };                                                                            \
  STAGE(0, 0);                                                                  \
  __syncthreads();                                                              \
  int cur = 0;                                                                  \
  for (int k0 = 0; k0 < K; k0 += BK) {                                          \
    if (k0 + BK < K) STAGE(cur ^ 1, k0 + BK);                                   \
    bf16x8 af[4], bfr[4];                                                       \
    _Pragma("unroll")                                                           \
    for (int m = 0; m < 4; m++)                                                 \
      af[m] = *(const bf16x8*)((const char*)As[cur] +                           \
               (wr + m * 16 + q) * 64 + (g << 4));                              \
    _Pragma("unroll")                                                           \
    for (int n = 0; n < 4; n++)                                                 \
      bfr[n] = *(const bf16x8*)((const char*)Bs[cur] +                          \
               (wc + n * 16 + q) * 64 + (g << 4));                              \
    _Pragma("unroll")                                                           \
    for (int m = 0; m < 4; m++)                                                 \
      _Pragma("unroll")                                                         \
      for (int n = 0; n < 4; n++)                                               \
        acc[m][n] = __builtin_amdgcn_mfma_f32_16x16x32_bf16(af[m], bfr[n], acc[m][n], 0, 0, 0); \
    __syncthreads();                                                            \
    cur ^= 1;                                                                   \
  }

// fp32-out GEMM (O-projection)
__global__ __launch_bounds__(256) void gemm_bt(const u16* __restrict__ A,
                                               const u16* __restrict__ Bw,
                                               float* __restrict__ C,
                                               int M, int N, int K) {
  GEMM_MAIN
#pragma unroll
  for (int m = 0; m < 4; m++) {
    const int r0 = m0 + wr + m * 16 + g * 4;
#pragma unroll
    for (int n = 0; n < 4; n++) {
      const int c = n0 + wc + n * 16 + q;
#pragma unroll
      for (int j = 0; j < 4; j++)
        C[(size_t)(r0 + j) * N + c] = acc[m][n][j];
    }
  }
}

// QKV GEMM with fused RMSNorm + RoPE epilogue (bf16 out).
__global__ __launch_bounds__(256) void gemm_qkv(const u16* __restrict__ A,
                                                const u16* __restrict__ Bw,
                                                u16* __restrict__ C,
                                                const float* __restrict__ cosT,
                                                const float* __restrict__ sinT,
                                                const float* __restrict__ qwv,
                                                const float* __restrict__ kwv,
                                                float qscale,
                                                int M, int N, int K) {
  GEMM_MAIN
  const int hcol = (n0 + wc) >> 6;
  const bool isV = hcol >= 40;
  const bool isQ = hcol < 32;
  const float osc = isQ ? qscale : 1.0f;
  float wgt[4] = {1.f, 1.f, 1.f, 1.f};
  if (!isV) {
    const float* wp = isQ ? qwv : kwv;
#pragma unroll
    for (int n = 0; n < 4; n++) wgt[n] = wp[n * 16 + q];
  }
#pragma unroll
  for (int m = 0; m < 4; m++) {
#pragma unroll
    for (int j = 0; j < 4; j++) {
      const int row = m0 + wr + m * 16 + g * 4 + j;
      float v[4];
#pragma unroll
      for (int n = 0; n < 4; n++) v[n] = acc[m][n][j];
      if (!isV) {
        float ss = v[0] * v[0] + v[1] * v[1] + v[2] * v[2] + v[3] * v[3];
        ss += __shfl_xor(ss, 1, 64);
        ss += __shfl_xor(ss, 2, 64);
        ss += __shfl_xor(ss, 4, 64);
        ss += __shfl_xor(ss, 8, 64);
        const float inv = rsqrtf(ss * (1.0f / 64.0f) + 1e-6f);
        const int s = row & (S_ - 1);
        float xn[4];
#pragma unroll
        for (int n = 0; n < 4; n++) xn[n] = v[n] * inv * wgt[n];
#pragma unroll
        for (int n = 0; n < 4; n++) {
          const float rot = (n < 2) ? -xn[n + 2] : xn[n - 2];
          const int d = n * 16 + q;
          v[n] = (xn[n] * cosT[s * 64 + d] + rot * sinT[s * 64 + d]) * osc;
        }
      }
#pragma unroll
      for (int n = 0; n < 4; n++)
        C[(size_t)row * N + (n0 + wc + n * 16 + q)] = f2bf(v[n]);
    }
  }
}

// -------- V: bf16 QKV v-part (b,s,kvh,d) -> bf16 (b,kvh,d,s) ---------------
__global__ void v_transpose(const u16* __restrict__ QKV, u16* __restrict__ Vt) {
  __shared__ u16 tile[64][72];
  const int s0 = blockIdx.x * 64;
  const int bk = blockIdx.y;
  const int b = bk / KVH_, kvh = bk % KVH_;
  const int t = threadIdx.x;
#pragma unroll
  for (int it = 0; it < 16; it++) {
    int idx = it * 256 + t;
    int sl = idx >> 6, d = idx & 63;
    tile[sl][d] = QKV[(size_t)(b * S_ + s0 + sl) * NQK_ + 2560 + kvh * 64 + d];
  }
  __syncthreads();
#pragma unroll
  for (int it = 0; it < 16; it++) {
    int idx = it * 256 + t;
    int d = idx >> 6, sl = idx & 63;
    Vt[(((size_t)(b * KVH_ + kvh)) * HD_ + d) * S_ + s0 + sl] = tile[sl][d];
  }
}

// ---------------- flash attention (shared-operand dual-tile loop) -----------
// Constant-shift softmax (exp2(s-12), shift in MFMA C-init). Dual phase
// (kt<=qlo): K fragments read ONCE feeding both tiles' QK back-to-back;
// Psm reused sequentially (L pack/read, then H) to stay at 40KB / 4 blk/CU;
// L's PV overlaps H's P-pack.
__global__ __launch_bounds__(256, 4) void attn_fwd(const u16* __restrict__ QKV,
                                                   const u16* __restrict__ Vt,
                                                   u16* __restrict__ Out) {
  __shared__ u16 Ksm[2][64 * 64];   // [key][d], XOR-swizzled 128B rows
  __shared__ u16 Vsm[2][64 * 64];   // [d][key], XOR-swizzled 128B rows
  __shared__ u16 Psm[4][16 * 64];   // per-wave P tile [q][kk], swizzled

  const int t = threadIdx.x, lane = t & 63, w = t >> 6;
  const int q = lane & 15, g = lane >> 4;

  const int fid = blockIdx.y * 16 + blockIdx.x;   // 0..1023
  const int xcd = fid & 7, slot = fid >> 3;       // slot 0..127
  const int kg = xcd * 2 + (slot >> 6);           // (b,kvh) group 0..15
  const int sub = slot & 63;
  const int ip = sub >> 2;                        // q-tile pair index 0..15
  const int b = kg >> 3, kvh = kg & 7;
  const int h = kvh * 4 + (sub & 3);

  const char* Kb = (const char*)(QKV + (size_t)b * S_ * NQK_ + 2048 + kvh * 64);
  const char* Vb = (const char*)(Vt + ((size_t)(b * KVH_ + kvh)) * HD_ * S_);

  const int SP0 = t * 16, SP1 = 4096 + t * 16;
  const int srow0 = SP0 >> 7, scb0 = (SP0 ^ ((srow0 & 7) << 4)) & 127;
  const int srow1 = SP1 >> 7, scb1 = (SP1 ^ ((srow1 & 7) << 4)) & 127;
  const int SB0 = (w << 10), SB1 = 4096 + (w << 10);
  const size_t KROW = (size_t)NQK_ * 2;

  auto STAGE = [&](int buf, int kt) {
    gload16(Kb + (size_t)(kt * 64 + srow0) * KROW + scb0, (char*)Ksm[buf] + SB0);
    gload16(Kb + (size_t)(kt * 64 + srow1) * KROW + scb1, (char*)Ksm[buf] + SB1);
    gload16(Vb + (size_t)srow0 * (S_ * 2) + (size_t)kt * 128 + scb0, (char*)Vsm[buf] + SB0);
    gload16(Vb + (size_t)srow1 * (S_ * 2) + (size_t)kt * 128 + scb1, (char*)Vsm[buf] + SB1);
  };

  const int swz = (q & 7) << 4;
  int koff[4][2], pwoff[4][2], proff[2];
#pragma unroll
  for (int nt = 0; nt < 4; nt++)
#pragma unroll
    for (int hh = 0; hh < 2; hh++) {
      koff[nt][hh] = ((nt * 16 + q) * 128 + hh * 64 + g * 16) ^ swz;
      pwoff[nt][hh] = (q * 128 + nt * 32 + g * 8 + hh * 4) ^ swz;
    }
#pragma unroll
  for (int c = 0; c < 2; c++) proff[c] = (q * 128 + c * 64 + g * 16) ^ swz;

  bf16x8 ones;
#pragma unroll
  for (int j = 0; j < 8; j++) ones[j] = (short)0x3F80;

  const int qlo = ip, qhi = 31 - ip;

  bf16x8 aqL[2], aqH[2];
  {
    const u16* qpL = QKV + (size_t)(b * S_ + qlo * 64 + w * 16 + q) * NQK_ + h * 64 + g * 8;
    const u16* qpH = QKV + (size_t)(b * S_ + qhi * 64 + w * 16 + q) * NQK_ + h * 64 + g * 8;
    aqL[0] = *(const bf16x8*)qpL;
    aqL[1] = *(const bf16x8*)(qpL + 32);
    aqH[0] = *(const bf16x8*)qpH;
    aqH[1] = *(const bf16x8*)(qpH + 32);
  }

  f32x4 oL[4] = {}, oH[4] = {};
  f32x4 lL = {}, lH = {};

  int cur = 0;

  // single-tile step (used when only the high tile is active)
  auto tile_step = [&](int kt, int qt, const bf16x8* aq, f32x4* o_acc, f32x4& l_acc) {
    f32x4 sc[4];
    __builtin_amdgcn_s_setprio(1);
#pragma unroll
    for (int nt = 0; nt < 4; nt++) {
      f32x4 s = {-12.0f, -12.0f, -12.0f, -12.0f};
#pragma unroll
      for (int hh = 0; hh < 2; hh++) {
        bf16x8 bk = *(const bf16x8*)((const char*)Ksm[cur] + koff[nt][hh]);
        s = __builtin_amdgcn_mfma_f32_16x16x32_bf16(bk, aq[hh], s, 0, 0, 0);
      }
      sc[nt] = s;
    }
    __builtin_amdgcn_s_setprio(0);

    if (kt == qt) {
#pragma unroll
      for (int nt = 0; nt < 4; nt++)
#pragma unroll
        for (int r = 0; r < 4; r++)
          if (nt * 16 + g * 4 + r > w * 16 + q) sc[nt][r] = -1e30f;
    }

#pragma unroll
    for (int nt = 0; nt < 4; nt++)
#pragma unroll
      for (int r = 0; r < 4; r++) sc[nt][r] = exp2f(sc[nt][r]);
#pragma unroll
    for (int nt = 0; nt < 4; nt++)
#pragma unroll
      for (int hh = 0; hh < 2; hh++) {
        u32 wv;
        asm("v_cvt_pk_bf16_f32 %0, %1, %2"
            : "=v"(wv) : "v"(sc[nt][2 * hh]), "v"(sc[nt][2 * hh + 1]));
        *(u32*)((char*)Psm[w] + pwoff[nt][hh]) = wv;
      }

    asm volatile("s_waitcnt lgkmcnt(0)" ::: "memory");
    __builtin_amdgcn_sched_barrier(0);

    bf16x8 pa[2];
#pragma unroll
    for (int c = 0; c < 2; c++)
      pa[c] = *(const bf16x8*)((const char*)Psm[w] + proff[c]);

    __builtin_amdgcn_s_setprio(1);
    l_acc = __builtin_amdgcn_mfma_f32_16x16x32_bf16(pa[0], ones, l_acc, 0, 0, 0);
    l_acc = __builtin_amdgcn_mfma_f32_16x16x32_bf16(pa[1], ones, l_acc, 0, 0, 0);
#pragma unroll
    for (int c = 0; c < 2; c++)
#pragma unroll
      for (int dt = 0; dt < 4; dt++) {
        bf16x8 bv = *(const bf16x8*)((const char*)Vsm[cur] + koff[dt][c]);
        o_acc[dt] = __builtin_amdgcn_mfma_f32_16x16x32_bf16(pa[c], bv, o_acc[dt], 0, 0, 0);
      }
    __builtin_amdgcn_s_setprio(0);
  };

  STAGE(0, 0);
  __syncthreads();

  for (int kt = 0; kt <= qhi; kt++) {
    if (kt < qhi) STAGE(cur ^ 1, kt + 1);

    if (kt <= qlo) {
      // ---- dual step: shared K fragments feed both tiles' QK ----
      f32x4 scL[4], scH[4];
      __builtin_amdgcn_s_setprio(1);
#pragma unroll
      for (int nt = 0; nt < 4; nt++) {
        f32x4 sL = {-12.0f, -12.0f, -12.0f, -12.0f};
        f32x4 sH = {-12.0f, -12.0f, -12.0f, -12.0f};
#pragma unroll
        for (int hh = 0; hh < 2; hh++) {
          bf16x8 bk = *(const bf16x8*)((const char*)Ksm[cur] + koff[nt][hh]);
          sL = __builtin_amdgcn_mfma_f32_16x16x32_bf16(bk, aqL[hh], sL, 0, 0, 0);
          sH = __builtin_amdgcn_mfma_f32_16x16x32_bf16(bk, aqH[hh], sH, 0, 0, 0);
        }
        scL[nt] = sL; scH[nt] = sH;
      }
      __builtin_amdgcn_s_setprio(0);

      if (kt == qlo) {  // low-tile diagonal mask (high tile: qhi > qlo here)
#pragma unroll
        for (int nt = 0; nt < 4; nt++)
#pragma unroll
          for (int r = 0; r < 4; r++)
            if (nt * 16 + g * 4 + r > w * 16 + q) scL[nt][r] = -1e30f;
      }

#pragma unroll
      for (int nt = 0; nt < 4; nt++)
#pragma unroll
        for (int r = 0; r < 4; r++) {
          scL[nt][r] = exp2f(scL[nt][r]);
          scH[nt][r] = exp2f(scH[nt][r]);
        }

      // pack L -> Psm, read paL, drain, then reuse region for H
#pragma unroll
      for (int nt = 0; nt < 4; nt++)
#pragma unroll
        for (int hh = 0; hh < 2; hh++) {
          u32 wv;
          asm("v_cvt_pk_bf16_f32 %0, %1, %2"
              : "=v"(wv) : "v"(scL[nt][2 * hh]), "v"(scL[nt][2 * hh + 1]));
          *(u32*)((char*)Psm[w] + pwoff[nt][hh]) = wv;
        }
      asm volatile("s_waitcnt lgkmcnt(0)" ::: "memory");
      __builtin_amdgcn_sched_barrier(0);
      bf16x8 paL[2];
#pragma unroll
      for (int c = 0; c < 2; c++)
        paL[c] = *(const bf16x8*)((const char*)Psm[w] + proff[c]);
      asm volatile("s_waitcnt lgkmcnt(0)" ::: "memory");  // paL in regs before overwrite
      __builtin_amdgcn_sched_barrier(0);

      // pack H (overlaps L's l/PV below)
#pragma unroll
      for (int nt = 0; nt < 4; nt++)
#pragma unroll
        for (int hh = 0; hh < 2; hh++) {
          u32 wv;
          asm("v_cvt_pk_bf16_f32 %0, %1, %2"
              : "=v"(wv) : "v"(scH[nt][2 * hh]), "v"(scH[nt][2 * hh + 1]));
          *(u32*)((char*)Psm[w] + pwoff[nt][hh]) = wv;
        }

      __builtin_amdgcn_s_setprio(1);
      lL = __builtin_amdgcn_mfma_f32_16x16x32_bf16(paL[0], ones, lL, 0, 0, 0);
      lL = __builtin_amdgcn_mfma_f32_16x16x32_bf16(paL[1], ones, lL, 0, 0, 0);
#pragma unroll
      for (int c = 0; c < 2; c++)
#pragma unroll
        for (int dt = 0; dt < 4; dt++) {
          bf16x8 bv = *(const bf16x8*)((const char*)Vsm[cur] + koff[dt][c]);
          oL[dt] = __builtin_amdgcn_mfma_f32_16x16x32_bf16(paL[c], bv, oL[dt], 0, 0, 0);
        }
      __builtin_amdgcn_s_setprio(0);

      asm volatile("s_waitcnt lgkmcnt(0)" ::: "memory");  // H writes visible
      __builtin_amdgcn_sched_barrier(0);
      bf16x8 paH[2];
#pragma unroll
      for (int c = 0; c < 2; c++)
        paH[c] = *(const bf16x8*)((const char*)Psm[w] + proff[c]);

      __builtin_amdgcn_s_setprio(1);
      lH = __builtin_amdgcn_mfma_f32_16x16x32_bf16(paH[0], ones, lH, 0, 0, 0);
      lH = __builtin_amdgcn_mfma_f32_16x16x32_bf16(paH[1], ones, lH, 0, 0, 0);
#pragma unroll
      for (int c = 0; c < 2; c++)
#pragma unroll
        for (int dt = 0; dt < 4; dt++) {
          bf16x8 bv = *(const bf16x8*)((const char*)Vsm[cur] + koff[dt][c]);
          oH[dt] = __builtin_amdgcn_mfma_f32_16x16x32_bf16(paH[c], bv, oH[dt], 0, 0, 0);
        }
      __builtin_amdgcn_s_setprio(0);
    } else {
      tile_step(kt, qhi, aqH, oH, lH);
    }

    __syncthreads();
    cur ^= 1;
  }

  // epilogues: O /= l, write bf16 (b,s,h,d)
  auto write_out = [&](int qt, const f32x4* o_acc, const f32x4& l_acc) {
#pragma unroll
    for (int r = 0; r < 4; r++) {
      const int qg = qt * 64 + w * 16 + g * 4 + r;
      const float inv = 1.0f / l_acc[r];
#pragma unroll
      for (int dt = 0; dt < 4; dt++)
        Out[(((size_t)b * S_ + qg) * H_ + h) * HD_ + dt * 16 + q] =
            f2bf(o_acc[dt][r] * inv);
    }
  };
  write_out(qlo, oL, lL);
  write_out(qhi, oH, lH);
}

// ---------------- host launch ----------------
extern "C" void kernel_launch(void* const* d_in, const int* in_sizes, int n_in,
                              void* d_out, int out_size, void* d_ws, size_t ws_size,
                              hipStream_t stream) {
  const float* x  = (const float*)d_in[0];
  const float* rc = (const float*)d_in[1];
  const float* rs = (const float*)d_in[2];
  const float* Wq = (const float*)d_in[3];
  const float* Wk = (const float*)d_in[4];
  const float* Wv = (const float*)d_in[5];
  const float* Wo = (const float*)d_in[6];
  const float* qw = (const float*)d_in[7];
  const float* kw = (const float*)d_in[8];
  float* out = (float*)d_out;

  char* ws = (char*)d_ws;
  const size_t MB = (size_t)1 << 20;
  u16* xb   = (u16*)(ws + 0 * MB);    // 16 MB bf16 x (reused as attn-out)
  u16* wbq  = (u16*)(ws + 16 * MB);   // 12 MB bf16 [Wq;Wk;Wv]
  u16* wbo  = (u16*)(ws + 28 * MB);   // 8 MB  bf16 Wo
  u16* QKVb = (u16*)(ws + 36 * MB);   // 24 MB bf16 QKV proj (b,s,3072)
  u16* Vtb  = (u16*)(ws + 60 * MB);   // 4 MB  bf16 V (b,kvh,d,s) -> 64 MB
  u16* AO   = xb;

  const int MT = B_ * S_;
  const float QSC = 0.125f * 1.44269504089f;  // (1/sqrt(64)) * log2(e)

  // one fused convert pass: x, Wq, Wk, Wv, Wo -> bf16
  cvt_all<<<dim3(2048), 256, 0, stream>>>(x, Wq, Wk, Wv, Wo, xb, wbq, wbo);

  // QKV projection with fused RMSNorm+RoPE epilogue (Q scaled by log2e/8)
  gemm_qkv<<<dim3(NQK_ / BN, MT / BM), 256, 0, stream>>>(
      xb, wbq, QKVb, rc, rs, qw, kw, QSC, MT, NQK_, DM_);

  // V -> (b,kvh,d,s)
  v_transpose<<<dim3(S_ / 64, B_ * KVH_), 256, 0, stream>>>(QKVb, Vtb);

  // attention (shared-operand dual-tile loop, 1024 balanced blocks)
  attn_fwd<<<dim3(16, 64), 256, 0, stream>>>(QKVb, Vtb, AO);

  // output projection -> d_out (fp32)
  gemm_bt<<<dim3(DM_ / BN, MT / BM), 256, 0, stream>>>(AO, wbo, out, MT, DM_, DM_);
}

// Round 13
// 199.224 us; speedup vs baseline: 1.3629x; 1.3629x over previous
//
#include <hip/hip_runtime.h>
#include <stdint.h>

#define B_ 2
#define S_ 2048
#define DM_ 2048
#define H_ 32
#define KVH_ 8
#define HD_ 64
#define NQK_ 3072   // 2048 q + 512 k + 512 v

typedef unsigned short u16;
typedef unsigned int u32;
typedef __attribute__((ext_vector_type(8))) short bf16x8;
typedef __attribute__((ext_vector_type(4))) float f32x4;

static __device__ __forceinline__ u16 f2bf(float f) {
  unsigned int u = __float_as_uint(f);
  u = (u + 0x7fffu + ((u >> 16) & 1u)) >> 16;
  return (u16)u;
}

// global -> LDS direct (width 16). LDS dest = wave-uniform base + lane*16.
static __device__ __forceinline__ void gload16(const void* g, void* lds_wave_base) {
  __builtin_amdgcn_global_load_lds(
      (__attribute__((address_space(1))) unsigned int*)(uintptr_t)g,
      (__attribute__((address_space(3))) unsigned int*)(uintptr_t)lds_wave_base,
      16, 0, 0);
}

// ---------------- fused fp32 -> bf16 convert (x, Wq, Wk, Wv, Wo) -----------
__global__ void cvt_all(const float* __restrict__ x, const float* __restrict__ wq,
                        const float* __restrict__ wk, const float* __restrict__ wv,
                        const float* __restrict__ wo,
                        u16* __restrict__ xb, u16* __restrict__ wbq,
                        u16* __restrict__ wbo) {
  const int NX = 2097152, NQ = 1048576, NKV = 262144;  // float4 counts
  const int TOT = NX + NQ + 2 * NKV + NQ;              // 4718592
  const int stride = gridDim.x * 256;
  for (int i = blockIdx.x * 256 + threadIdx.x; i < TOT; i += stride) {
    const float4* s; ushort4* d; int off;
    if (i < NX)                { s = (const float4*)x;  d = (ushort4*)xb;  off = i; }
    else if (i < NX + NQ)      { s = (const float4*)wq; d = (ushort4*)wbq; off = i - NX; }
    else if (i < NX + NQ + NKV){ s = (const float4*)wk; d = (ushort4*)(wbq + (size_t)DM_ * DM_); off = i - NX - NQ; }
    else if (i < NX + NQ + 2 * NKV) { s = (const float4*)wv; d = (ushort4*)(wbq + (size_t)DM_ * DM_ + (size_t)512 * DM_); off = i - NX - NQ - NKV; }
    else                       { s = (const float4*)wo; d = (ushort4*)wbo; off = i - NX - NQ - 2 * NKV; }
    const float4 v = s[off];
    ushort4 o;
    o.x = f2bf(v.x); o.y = f2bf(v.y); o.z = f2bf(v.z); o.w = f2bf(v.w);
    d[off] = o;
  }
}

// ---------------- GEMM: C(MxN) = A(MxK) * B(NxK)^T, bf16 in ----------------
// 2-phase double-buffered 128x128 (measured best structure) with T1
// bijective XCD-chunked block remap (grid counts divisible by 8): each XCD
// covers a contiguous slab of output rows -> A-panel L2 reuse.
#define BM 128
#define BN 128
#define BK 32

#define GEMM_MAIN                                                               \
  __shared__ u16 As[2][BM * BK];                                                \
  __shared__ u16 Bs[2][BN * BK];                                                \
  const int t = threadIdx.x;                                                    \
  const int lane = t & 63;                                                      \
  const int w = t >> 6;                                                         \
  const int q = lane & 15, g = lane >> 4;                                       \
  const int wr = (w >> 1) * 64, wc = (w & 1) * 64;                              \
  const int fidg = blockIdx.y * gridDim.x + blockIdx.x;                         \
  const int cpxg = (gridDim.x * gridDim.y) >> 3;                                \
  const int swg = (fidg & 7) * cpxg + (fidg >> 3);                              \
  const int m0 = (swg / gridDim.x) * BM;                                        \
  const int n0 = (swg % gridDim.x) * BN;                                        \
  f32x4 acc[4][4] = {};                                                         \
  const char* Ab = (const char*)A;                                              \
  const char* Bb = (const char*)Bw;                                             \
  const size_t K2 = (size_t)K * 2;                                              \
  const int P0 = t * 16;                                                        \
  const int row0 = P0 >> 6, kb0 = P0 & 63;                                      \
  const int P1 = 4096 + t * 16;                                                 \
  const int row1 = P1 >> 6, kb1 = P1 & 63;                                      \
  const int Pb0 = (w << 10), Pb1 = 4096 + (w << 10);                            \
  auto STAGE = [&](int buf, int k0) {                                           \
    gload16(Ab + (size_t)(m0 + row0) * K2 + (size_t)k0 * 2 + kb0, (char*)As[buf] + Pb0); \
    gload16(Ab + (size_t)(m0 + row1) * K2 + (size_t)k0 * 2 + kb1, (char*)As[buf] + Pb1); \
    gload16(Bb + (size_t)(n0 + row0) * K2 + (size_t)k0 * 2 + kb0, (char*)Bs[buf] + Pb0); \
    gload16(Bb + (size_t)(n0 + row1) * K2 + (size_t)k0 * 2 + kb1, (char*)Bs[buf] + Pb1); \
  };                                                                            \
  STAGE(0, 0);                                                                  \
  __syncthreads();                                                              \
  int cur = 0;                                                                  \
  for (int k0 = 0; k0 < K; k0 += BK) {                                          \
    if (k0 + BK < K) STAGE(cur ^ 1, k0 + BK);                                   \
    bf16x8 af[4], bfr[4];                                                       \
    _Pragma("unroll")                                                           \
    for (int m = 0; m < 4; m++)                                                 \
      af[m] = *(const bf16x8*)((const char*)As[cur] +                           \
               (wr + m * 16 + q) * 64 + (g << 4));                              \
    _Pragma("unroll")                                                           \
    for (int n = 0; n < 4; n++)                                                 \
      bfr[n] = *(const bf16x8*)((const char*)Bs[cur] +                          \
               (wc + n * 16 + q) * 64 + (g << 4));                              \
    _Pragma("unroll")                                                           \
    for (int m = 0; m < 4; m++)                                                 \
      _Pragma("unroll")                                                         \
      for (int n = 0; n < 4; n++)                                               \
        acc[m][n] = __builtin_amdgcn_mfma_f32_16x16x32_bf16(af[m], bfr[n], acc[m][n], 0, 0, 0); \
    __syncthreads();                                                            \
    cur ^= 1;                                                                   \
  }

// fp32-out GEMM (O-projection)
__global__ __launch_bounds__(256) void gemm_bt(const u16* __restrict__ A,
                                               const u16* __restrict__ Bw,
                                               float* __restrict__ C,
                                               int M, int N, int K) {
  GEMM_MAIN
#pragma unroll
  for (int m = 0; m < 4; m++) {
    const int r0 = m0 + wr + m * 16 + g * 4;
#pragma unroll
    for (int n = 0; n < 4; n++) {
      const int c = n0 + wc + n * 16 + q;
#pragma unroll
      for (int j = 0; j < 4; j++)
        C[(size_t)(r0 + j) * N + c] = acc[m][n][j];
    }
  }
}

// QKV GEMM with fused RMSNorm + RoPE epilogue (bf16 out).
__global__ __launch_bounds__(256) void gemm_qkv(const u16* __restrict__ A,
                                                const u16* __restrict__ Bw,
                                                u16* __restrict__ C,
                                                const float* __restrict__ cosT,
                                                const float* __restrict__ sinT,
                                                const float* __restrict__ qwv,
                                                const float* __restrict__ kwv,
                                                float qscale,
                                                int M, int N, int K) {
  GEMM_MAIN
  const int hcol = (n0 + wc) >> 6;
  const bool isV = hcol >= 40;
  const bool isQ = hcol < 32;
  const float osc = isQ ? qscale : 1.0f;
  float wgt[4] = {1.f, 1.f, 1.f, 1.f};
  if (!isV) {
    const float* wp = isQ ? qwv : kwv;
#pragma unroll
    for (int n = 0; n < 4; n++) wgt[n] = wp[n * 16 + q];
  }
#pragma unroll
  for (int m = 0; m < 4; m++) {
#pragma unroll
    for (int j = 0; j < 4; j++) {
      const int row = m0 + wr + m * 16 + g * 4 + j;
      float v[4];
#pragma unroll
      for (int n = 0; n < 4; n++) v[n] = acc[m][n][j];
      if (!isV) {
        float ss = v[0] * v[0] + v[1] * v[1] + v[2] * v[2] + v[3] * v[3];
        ss += __shfl_xor(ss, 1, 64);
        ss += __shfl_xor(ss, 2, 64);
        ss += __shfl_xor(ss, 4, 64);
        ss += __shfl_xor(ss, 8, 64);
        const float inv = rsqrtf(ss * (1.0f / 64.0f) + 1e-6f);
        const int s = row & (S_ - 1);
        float xn[4];
#pragma unroll
        for (int n = 0; n < 4; n++) xn[n] = v[n] * inv * wgt[n];
#pragma unroll
        for (int n = 0; n < 4; n++) {
          const float rot = (n < 2) ? -xn[n + 2] : xn[n - 2];
          const int d = n * 16 + q;
          v[n] = (xn[n] * cosT[s * 64 + d] + rot * sinT[s * 64 + d]) * osc;
        }
      }
#pragma unroll
      for (int n = 0; n < 4; n++)
        C[(size_t)row * N + (n0 + wc + n * 16 + q)] = f2bf(v[n]);
    }
  }
}

// -------- V: bf16 QKV v-part (b,s,kvh,d) -> bf16 (b,kvh,d,s) ---------------
__global__ void v_transpose(const u16* __restrict__ QKV, u16* __restrict__ Vt) {
  __shared__ u16 tile[64][72];
  const int s0 = blockIdx.x * 64;
  const int bk = blockIdx.y;
  const int b = bk / KVH_, kvh = bk % KVH_;
  const int t = threadIdx.x;
#pragma unroll
  for (int it = 0; it < 16; it++) {
    int idx = it * 256 + t;
    int sl = idx >> 6, d = idx & 63;
    tile[sl][d] = QKV[(size_t)(b * S_ + s0 + sl) * NQK_ + 2560 + kvh * 64 + d];
  }
  __syncthreads();
#pragma unroll
  for (int it = 0; it < 16; it++) {
    int idx = it * 256 + t;
    int d = idx >> 6, sl = idx & 63;
    Vt[(((size_t)(b * KVH_ + kvh)) * HD_ + d) * S_ + s0 + sl] = tile[sl][d];
  }
}

// ---------------- flash attention (merged paired-tile kt loop, R11) ---------
// Constant-shift softmax (P = exp2(s-12), shift folded into MFMA C-init).
// Low tile (qt=ip) and high tile (qt=31-ip) share ONE kt loop: low active
// while kt<=ip (block-uniform), high always. One barrier + one staging per kt.
__global__ __launch_bounds__(256, 4) void attn_fwd(const u16* __restrict__ QKV,
                                                   const u16* __restrict__ Vt,
                                                   u16* __restrict__ Out) {
  __shared__ u16 Ksm[2][64 * 64];   // [key][d], XOR-swizzled 128B rows
  __shared__ u16 Vsm[2][64 * 64];   // [d][key], XOR-swizzled 128B rows
  __shared__ u16 Psm[4][16 * 64];   // per-wave P tile [q][kk], swizzled

  const int t = threadIdx.x, lane = t & 63, w = t >> 6;
  const int q = lane & 15, g = lane >> 4;

  const int fid = blockIdx.y * 16 + blockIdx.x;   // 0..1023
  const int xcd = fid & 7, slot = fid >> 3;       // slot 0..127
  const int kg = xcd * 2 + (slot >> 6);           // (b,kvh) group 0..15
  const int sub = slot & 63;
  const int ip = sub >> 2;                        // q-tile pair index 0..15
  const int b = kg >> 3, kvh = kg & 7;
  const int h = kvh * 4 + (sub & 3);

  const char* Kb = (const char*)(QKV + (size_t)b * S_ * NQK_ + 2048 + kvh * 64);
  const char* Vb = (const char*)(Vt + ((size_t)(b * KVH_ + kvh)) * HD_ * S_);

  const int SP0 = t * 16, SP1 = 4096 + t * 16;
  const int srow0 = SP0 >> 7, scb0 = (SP0 ^ ((srow0 & 7) << 4)) & 127;
  const int srow1 = SP1 >> 7, scb1 = (SP1 ^ ((srow1 & 7) << 4)) & 127;
  const int SB0 = (w << 10), SB1 = 4096 + (w << 10);
  const size_t KROW = (size_t)NQK_ * 2;

  auto STAGE = [&](int buf, int kt) {
    gload16(Kb + (size_t)(kt * 64 + srow0) * KROW + scb0, (char*)Ksm[buf] + SB0);
    gload16(Kb + (size_t)(kt * 64 + srow1) * KROW + scb1, (char*)Ksm[buf] + SB1);
    gload16(Vb + (size_t)srow0 * (S_ * 2) + (size_t)kt * 128 + scb0, (char*)Vsm[buf] + SB0);
    gload16(Vb + (size_t)srow1 * (S_ * 2) + (size_t)kt * 128 + scb1, (char*)Vsm[buf] + SB1);
  };

  const int swz = (q & 7) << 4;
  int koff[4][2], pwoff[4][2], proff[2];
#pragma unroll
  for (int nt = 0; nt < 4; nt++)
#pragma unroll
    for (int hh = 0; hh < 2; hh++) {
      koff[nt][hh] = ((nt * 16 + q) * 128 + hh * 64 + g * 16) ^ swz;
      pwoff[nt][hh] = (q * 128 + nt * 32 + g * 8 + hh * 4) ^ swz;
    }
#pragma unroll
  for (int c = 0; c < 2; c++) proff[c] = (q * 128 + c * 64 + g * 16) ^ swz;

  bf16x8 ones;
#pragma unroll
  for (int j = 0; j < 8; j++) ones[j] = (short)0x3F80;

  const int qlo = ip, qhi = 31 - ip;

  // Q fragments for both tiles
  bf16x8 aqL[2], aqH[2];
  {
    const u16* qpL = QKV + (size_t)(b * S_ + qlo * 64 + w * 16 + q) * NQK_ + h * 64 + g * 8;
    const u16* qpH = QKV + (size_t)(b * S_ + qhi * 64 + w * 16 + q) * NQK_ + h * 64 + g * 8;
    aqL[0] = *(const bf16x8*)qpL;
    aqL[1] = *(const bf16x8*)(qpL + 32);
    aqH[0] = *(const bf16x8*)qpH;
    aqH[1] = *(const bf16x8*)(qpH + 32);
  }

  f32x4 oL[4] = {}, oH[4] = {};
  f32x4 lL = {}, lH = {};

  int cur = 0;

  // one tile's full per-kt phase (QK -> mask -> exp2 -> P-LDS -> l,PV)
  auto tile_step = [&](int kt, int qt, const bf16x8* aq, f32x4* o_acc, f32x4& l_acc) {
    f32x4 sc[4];
    __builtin_amdgcn_s_setprio(1);
#pragma unroll
    for (int nt = 0; nt < 4; nt++) {
      f32x4 s = {-12.0f, -12.0f, -12.0f, -12.0f};  // softmax shift folded in
#pragma unroll
      for (int hh = 0; hh < 2; hh++) {
        bf16x8 bk = *(const bf16x8*)((const char*)Ksm[cur] + koff[nt][hh]);
        s = __builtin_amdgcn_mfma_f32_16x16x32_bf16(bk, aq[hh], s, 0, 0, 0);
      }
      sc[nt] = s;
    }
    __builtin_amdgcn_s_setprio(0);

    if (kt == qt) {  // diagonal-tile causal mask
#pragma unroll
      for (int nt = 0; nt < 4; nt++)
#pragma unroll
        for (int r = 0; r < 4; r++)
          if (nt * 16 + g * 4 + r > w * 16 + q) sc[nt][r] = -1e30f;
    }

    // P = exp2(s) in (0,1] (scores pre-shifted by -12; bound |s|<=11.6)
#pragma unroll
    for (int nt = 0; nt < 4; nt++)
#pragma unroll
      for (int r = 0; r < 4; r++) sc[nt][r] = exp2f(sc[nt][r]);
#pragma unroll
    for (int nt = 0; nt < 4; nt++)
#pragma unroll
      for (int hh = 0; hh < 2; hh++) {
        u32 wv;
        asm("v_cvt_pk_bf16_f32 %0, %1, %2"
            : "=v"(wv) : "v"(sc[nt][2 * hh]), "v"(sc[nt][2 * hh + 1]));
        *(u32*)((char*)Psm[w] + pwoff[nt][hh]) = wv;
      }

    asm volatile("s_waitcnt lgkmcnt(0)" ::: "memory");
    __builtin_amdgcn_sched_barrier(0);

    bf16x8 pa[2];
#pragma unroll
    for (int c = 0; c < 2; c++)
      pa[c] = *(const bf16x8*)((const char*)Psm[w] + proff[c]);

    __builtin_amdgcn_s_setprio(1);
    l_acc = __builtin_amdgcn_mfma_f32_16x16x32_bf16(pa[0], ones, l_acc, 0, 0, 0);
    l_acc = __builtin_amdgcn_mfma_f32_16x16x32_bf16(pa[1], ones, l_acc, 0, 0, 0);
#pragma unroll
    for (int c = 0; c < 2; c++)
#pragma unroll
      for (int dt = 0; dt < 4; dt++) {
        bf16x8 bv = *(const bf16x8*)((const char*)Vsm[cur] + koff[dt][c]);
        o_acc[dt] = __builtin_amdgcn_mfma_f32_16x16x32_bf16(pa[c], bv, o_acc[dt], 0, 0, 0);
      }
    __builtin_amdgcn_s_setprio(0);
  };

  STAGE(0, 0);
  __syncthreads();

  for (int kt = 0; kt <= qhi; kt++) {
    if (kt < qhi) STAGE(cur ^ 1, kt + 1);
    if (kt <= qlo) tile_step(kt, qlo, aqL, oL, lL);   // block-uniform branch
    tile_step(kt, qhi, aqH, oH, lH);
    __syncthreads();
    cur ^= 1;
  }

  // epilogues: O /= l, write bf16 (b,s,h,d)
  auto write_out = [&](int qt, const f32x4* o_acc, const f32x4& l_acc) {
#pragma unroll
    for (int r = 0; r < 4; r++) {
      const int qg = qt * 64 + w * 16 + g * 4 + r;
      const float inv = 1.0f / l_acc[r];
#pragma unroll
      for (int dt = 0; dt < 4; dt++)
        Out[(((size_t)b * S_ + qg) * H_ + h) * HD_ + dt * 16 + q] =
            f2bf(o_acc[dt][r] * inv);
    }
  };
  write_out(qlo, oL, lL);
  write_out(qhi, oH, lH);
}

// ---------------- host launch ----------------
extern "C" void kernel_launch(void* const* d_in, const int* in_sizes, int n_in,
                              void* d_out, int out_size, void* d_ws, size_t ws_size,
                              hipStream_t stream) {
  const float* x  = (const float*)d_in[0];
  const float* rc = (const float*)d_in[1];
  const float* rs = (const float*)d_in[2];
  const float* Wq = (const float*)d_in[3];
  const float* Wk = (const float*)d_in[4];
  const float* Wv = (const float*)d_in[5];
  const float* Wo = (const float*)d_in[6];
  const float* qw = (const float*)d_in[7];
  const float* kw = (const float*)d_in[8];
  float* out = (float*)d_out;

  char* ws = (char*)d_ws;
  const size_t MB = (size_t)1 << 20;
  u16* xb   = (u16*)(ws + 0 * MB);    // 16 MB bf16 x (reused as attn-out)
  u16* wbq  = (u16*)(ws + 16 * MB);   // 12 MB bf16 [Wq;Wk;Wv]
  u16* wbo  = (u16*)(ws + 28 * MB);   // 8 MB  bf16 Wo
  u16* QKVb = (u16*)(ws + 36 * MB);   // 24 MB bf16 QKV proj (b,s,3072)
  u16* Vtb  = (u16*)(ws + 60 * MB);   // 4 MB  bf16 V (b,kvh,d,s) -> 64 MB
  u16* AO   = xb;

  const int MT = B_ * S_;
  const float QSC = 0.125f * 1.44269504089f;  // (1/sqrt(64)) * log2(e)

  // one fused convert pass: x, Wq, Wk, Wv, Wo -> bf16
  cvt_all<<<dim3(2048), 256, 0, stream>>>(x, Wq, Wk, Wv, Wo, xb, wbq, wbo);

  // QKV projection with fused RMSNorm+RoPE epilogue (Q scaled by log2e/8)
  gemm_qkv<<<dim3(NQK_ / BN, MT / BM), 256, 0, stream>>>(
      xb, wbq, QKVb, rc, rs, qw, kw, QSC, MT, NQK_, DM_);

  // V -> (b,kvh,d,s)
  v_transpose<<<dim3(S_ / 64, B_ * KVH_), 256, 0, stream>>>(QKVb, Vtb);

  // attention (merged paired-tile loop, 1024 balanced blocks)
  attn_fwd<<<dim3(16, 64), 256, 0, stream>>>(QKVb, Vtb, AO);

  // output projection -> d_out (fp32)
  gemm_bt<<<dim3(DM_ / BN, MT / BM), 256, 0, stream>>>(AO, wbo, out, MT, DM_, DM_);
}